// Round 1
// baseline (314.906 us; speedup 1.0000x reference)
//
#include <hip/hip_runtime.h>
#include <math.h>

#define NB 16
#define NS 4096
#define NH 768
#define NG 16
#define WRAD 15
#define WLEN 31
#define NH4 192   // NH / 4 float4 columns
#define OUTW (1 + NG)

__device__ inline float4 f4max(float4 a, float4 b) {
    return make_float4(fmaxf(a.x, b.x), fmaxf(a.y, b.y), fmaxf(a.z, b.z), fmaxf(a.w, b.w));
}
__device__ inline float4 f4add(float4 a, float4 b) {
    return make_float4(a.x + b.x, a.y + b.y, a.z + b.z, a.w + b.w);
}
__device__ inline float f4dot(float4 a, float4 b) {
    return a.x * b.x + a.y * b.y + a.z * b.z + a.w * b.w;
}

// Block reduce (blockDim.x == 192): pad LDS to 256, power-of-2 tree.
__device__ inline float block_reduce_192(float v, float* sbuf) {
    int tid = threadIdx.x;
    sbuf[tid] = v;
    if (tid < 64) sbuf[192 + tid] = 0.0f;
    __syncthreads();
    for (int off = 128; off > 0; off >>= 1) {
        if (tid < off) sbuf[tid] += sbuf[tid + off];
        __syncthreads();
    }
    float r = sbuf[0];
    __syncthreads();
    return r;
}

// ---------------------------------------------------------------------------
// Kernel A: masked partial max/sum over s-chunks of sequence_output.
// grid = (nchunks, NB), block = 192. Thread t owns float4 column t.
// ---------------------------------------------------------------------------
__global__ __launch_bounds__(192) void text_partial_kernel(
    const float* __restrict__ seq, const int* __restrict__ tt,
    const int* __restrict__ wm, float* __restrict__ pmax,
    float* __restrict__ psum, int chunk, int nchunks) {
    const int ss = blockIdx.x;
    const int b = blockIdx.y;
    const int tid = threadIdx.x;
    const int s0 = ss * chunk;

    __shared__ unsigned char valid[1024];
    for (int i = tid; i < chunk; i += blockDim.x) {
        const int s = s0 + i;
        valid[i] = (tt[b * NS + s] == 0) && (wm[b * NS + s] != 0);
    }
    __syncthreads();

    const float4* rowbase = (const float4*)(seq + (size_t)b * NS * NH);
    float4 mx = make_float4(-INFINITY, -INFINITY, -INFINITY, -INFINITY);
    float4 sm = make_float4(0.f, 0.f, 0.f, 0.f);
    for (int i = 0; i < chunk; ++i) {
        if (valid[i]) {  // wave-uniform branch
            float4 v = rowbase[(size_t)(s0 + i) * NH4 + tid];
            mx = f4max(mx, v);
            sm = f4add(sm, v);
        }
    }
    const size_t o = ((size_t)(b * nchunks + ss)) * NH4 + tid;
    ((float4*)pmax)[o] = mx;
    ((float4*)psum)[o] = sm;
}

// ---------------------------------------------------------------------------
// Kernel B: per-batch cls score. grid = NB, block = 192.
// ---------------------------------------------------------------------------
__global__ __launch_bounds__(192) void cls_kernel(
    const float* __restrict__ pooled, const int* __restrict__ tt,
    const int* __restrict__ wm, const float* __restrict__ pmax,
    const float* __restrict__ psum, const float* __restrict__ clsW,
    const float* __restrict__ clsb, float* __restrict__ out, int nchunks) {
    const int b = blockIdx.x;
    const int tid = threadIdx.x;
    __shared__ float sbuf[256];

    // base_mask count over the full sequence
    float cnt = 0.f;
    for (int s = tid; s < NS; s += blockDim.x)
        cnt += (float)((tt[b * NS + s] == 0) && (wm[b * NS + s] != 0));
    const float count = block_reduce_192(cnt, sbuf);

    // combine partials for this thread's float4 column
    const float4* pm4 = (const float4*)pmax;
    const float4* ps4 = (const float4*)psum;
    float4 mx = make_float4(-INFINITY, -INFINITY, -INFINITY, -INFINITY);
    float4 sm = make_float4(0.f, 0.f, 0.f, 0.f);
    for (int c = 0; c < nchunks; ++c) {
        const size_t o = ((size_t)(b * nchunks + c)) * NH4 + tid;
        mx = f4max(mx, pm4[o]);
        sm = f4add(sm, ps4[o]);
    }
    const float4 zero4 = make_float4(0.f, 0.f, 0.f, 0.f);
    float4 tmax = f4max(mx, zero4);
    float4 tavg = make_float4(sm.x / count, sm.y / count, sm.z / count, sm.w / count);

    const float4* p4 = (const float4*)(pooled + (size_t)b * NH);
    const float4* w0 = (const float4*)clsW;
    const float4* w1 = (const float4*)(clsW + NH);
    const float4* w2 = (const float4*)(clsW + 2 * NH);
    float part = f4dot(p4[tid], w0[tid]) + f4dot(tmax, w1[tid]) + f4dot(tavg, w2[tid]);
    float total = block_reduce_192(part, sbuf);
    if (tid == 0) out[b * OUTW + 0] = total + clsb[0];
}

// ---------------------------------------------------------------------------
// Kernel C: per-(b,g) gap score. grid = NB*NG, block = 192.
// ---------------------------------------------------------------------------
__global__ __launch_bounds__(192) void gap_kernel(
    const float* __restrict__ seq, const int* __restrict__ tt,
    const int* __restrict__ wm, const int* __restrict__ gids,
    const float* __restrict__ gapW, const float* __restrict__ gapb,
    float* __restrict__ out) {
    const int bg = blockIdx.x;
    const int b = bg / NG;
    const int g = bg % NG;
    const int tid = threadIdx.x;

    __shared__ int s_gid;
    __shared__ int s_valid[WLEN];
    __shared__ float s_cnt;
    __shared__ float sbuf[256];

    if (tid == 0) s_gid = gids[b * NG + g];
    __syncthreads();
    const int gi = s_gid;
    if (tid < WLEN) {
        const int idx = gi - WRAD + tid;
        s_valid[tid] = (idx >= 0 && idx < NS && tt[b * NS + idx] == 0 &&
                        wm[b * NS + idx] != 0) ? 1 : 0;
    }
    __syncthreads();
    if (tid == 0) {
        int c = 0;
        for (int j = 0; j < WLEN; ++j) c += s_valid[j];
        s_cnt = (float)c;
    }
    __syncthreads();
    const float count = s_cnt;

    const float4* rowbase = (const float4*)(seq + (size_t)b * NS * NH);
    const float4 gv = rowbase[(size_t)gi * NH4 + tid];

    float4 mx = make_float4(-INFINITY, -INFINITY, -INFINITY, -INFINITY);
    float4 sm = make_float4(0.f, 0.f, 0.f, 0.f);
    for (int j = 0; j < WLEN; ++j) {
        if (s_valid[j]) {  // wave-uniform branch
            float4 v = rowbase[(size_t)(gi - WRAD + j) * NH4 + tid];
            mx = f4max(mx, v);
            sm = f4add(sm, v);
        }
    }
    const float4 zero4 = make_float4(0.f, 0.f, 0.f, 0.f);
    float4 wmax = f4max(mx, zero4);
    // Deliberately plain division: count==0 yields 0/0 = NaN, matching the
    // reference's masked-average semantics in that (practically impossible) case.
    float4 wavg = make_float4(sm.x / count, sm.y / count, sm.z / count, sm.w / count);

    const float4* w0 = (const float4*)gapW;
    const float4* w1 = (const float4*)(gapW + NH);
    const float4* w2 = (const float4*)(gapW + 2 * NH);
    float part = f4dot(gv, w0[tid]) + f4dot(wmax, w1[tid]) + f4dot(wavg, w2[tid]);
    float total = block_reduce_192(part, sbuf);
    if (tid == 0) out[b * OUTW + 1 + g] = total + gapb[0];
}

extern "C" void kernel_launch(void* const* d_in, const int* in_sizes, int n_in,
                              void* d_out, int out_size, void* d_ws, size_t ws_size,
                              hipStream_t stream) {
    const float* seq    = (const float*)d_in[0];  // [B,S,H] fp32
    const float* pooled = (const float*)d_in[1];  // [B,H]
    const int*   tt     = (const int*)d_in[2];    // [B,S]
    const int*   wm     = (const int*)d_in[3];    // [B,S]
    const int*   gids   = (const int*)d_in[4];    // [B,G]
    const float* gapW   = (const float*)d_in[5];  // [3H]
    const float* gapb   = (const float*)d_in[6];  // scalar
    const float* clsW   = (const float*)d_in[7];  // [3H]
    const float* clsb   = (const float*)d_in[8];  // scalar
    float* out = (float*)d_out;

    // Pick nchunks to fit workspace: need 2 * nchunks * NB * NH floats.
    int nchunks = 64;
    while (nchunks > 4 &&
           (size_t)nchunks * NB * NH * 2 * sizeof(float) > ws_size)
        nchunks >>= 1;
    const int chunk = NS / nchunks;

    float* pmax = (float*)d_ws;
    float* psum = pmax + (size_t)nchunks * NB * NH;

    text_partial_kernel<<<dim3(nchunks, NB), 192, 0, stream>>>(
        seq, tt, wm, pmax, psum, chunk, nchunks);
    gap_kernel<<<NB * NG, 192, 0, stream>>>(seq, tt, wm, gids, gapW, gapb, out);
    cls_kernel<<<NB, 192, 0, stream>>>(pooled, tt, wm, pmax, psum, clsW, clsb,
                                       out, nchunks);
}

// Round 2
// 286.724 us; speedup vs baseline: 1.0983x; 1.0983x over previous
//
#include <hip/hip_runtime.h>
#include <math.h>

#define NB 16
#define NS 4096
#define NH 768
#define NG 16
#define WRAD 15
#define WLEN 31
#define NH4 192     // NH / 4 float4 columns
#define OUTW (1 + NG)
#define NCH 32      // s-chunks per batch
#define CHUNK 128   // NS / NCH

__device__ inline float4 f4max(float4 a, float4 b) {
    return make_float4(fmaxf(a.x, b.x), fmaxf(a.y, b.y), fmaxf(a.z, b.z), fmaxf(a.w, b.w));
}
__device__ inline float4 f4add(float4 a, float4 b) {
    return make_float4(a.x + b.x, a.y + b.y, a.z + b.z, a.w + b.w);
}
__device__ inline float f4dot(float4 a, float4 b) {
    return a.x * b.x + a.y * b.y + a.z * b.z + a.w * b.w;
}

// Block reduce (blockDim.x == 192): pad LDS to 256, power-of-2 tree.
__device__ inline float block_reduce_192(float v, float* sbuf) {
    int tid = threadIdx.x;
    sbuf[tid] = v;
    if (tid < 64) sbuf[192 + tid] = 0.0f;
    __syncthreads();
    for (int off = 128; off > 0; off >>= 1) {
        if (tid < off) sbuf[tid] += sbuf[tid + off];
        __syncthreads();
    }
    float r = sbuf[0];
    __syncthreads();
    return r;
}

// ---------------------------------------------------------------------------
// Fused kernel: blocks [0, NB*NCH) do masked text partials (compacted,
// branch-free inner loop); blocks [NB*NCH, NB*NCH+NB*NG) do gap scores.
// block = 192 threads; thread t owns float4 column t.
// ---------------------------------------------------------------------------
__global__ __launch_bounds__(192) void fused_kernel(
    const float* __restrict__ seq, const int* __restrict__ tt,
    const int* __restrict__ wm, const int* __restrict__ gids,
    const float* __restrict__ gapW, const float* __restrict__ gapb,
    float* __restrict__ pmax, float* __restrict__ psum,
    int* __restrict__ pcnt, float* __restrict__ out) {
    const int blk = blockIdx.x;
    const int tid = threadIdx.x;

    __shared__ float sbuf[256];
    __shared__ int s_idx[CHUNK];
    __shared__ unsigned long long s_wmask[2];
    __shared__ int s_misc[2];

    const float4 ninf4 = make_float4(-INFINITY, -INFINITY, -INFINITY, -INFINITY);
    const float4 zero4 = make_float4(0.f, 0.f, 0.f, 0.f);

    if (blk < NB * NCH) {
        // ---------------- text partial ----------------
        const int b = blk / NCH;
        const int ss = blk % NCH;
        const int s0 = ss * CHUNK;

        // evaluate mask (waves 0,1 fully active), ballot per wave
        if (tid < CHUNK) {
            const int s = s0 + tid;
            bool v = (tt[b * NS + s] == 0) && (wm[b * NS + s] != 0);
            unsigned long long m = __ballot(v);
            if ((tid & 63) == 0) s_wmask[tid >> 6] = m;
        }
        __syncthreads();
        // compact valid row indices into s_idx
        if (tid < CHUNK) {
            const int w = tid >> 6, l = tid & 63;
            const unsigned long long m = s_wmask[w];
            if ((m >> l) & 1ull) {
                int pos = (w ? __popcll(s_wmask[0]) : 0) +
                          __popcll(m & ((1ull << l) - 1ull));
                s_idx[pos] = s0 + tid;
            }
        }
        if (tid == 0)
            s_misc[0] = __popcll(s_wmask[0]) + __popcll(s_wmask[1]);
        __syncthreads();
        const int n = s_misc[0];

        const float4* rowbase = (const float4*)(seq + (size_t)b * NS * NH);
        float4 mx = ninf4;
        float4 sm = zero4;
        int i = 0;
        for (; i + 4 <= n; i += 4) {  // unconditional, 4 loads in flight
            const int i0 = s_idx[i], i1 = s_idx[i + 1], i2 = s_idx[i + 2], i3 = s_idx[i + 3];
            float4 v0 = rowbase[(size_t)i0 * NH4 + tid];
            float4 v1 = rowbase[(size_t)i1 * NH4 + tid];
            float4 v2 = rowbase[(size_t)i2 * NH4 + tid];
            float4 v3 = rowbase[(size_t)i3 * NH4 + tid];
            mx = f4max(mx, f4max(f4max(v0, v1), f4max(v2, v3)));
            sm = f4add(sm, f4add(f4add(v0, v1), f4add(v2, v3)));
        }
        for (; i < n; ++i) {
            float4 v = rowbase[(size_t)s_idx[i] * NH4 + tid];
            mx = f4max(mx, v);
            sm = f4add(sm, v);
        }
        const size_t o = ((size_t)(b * NCH + ss)) * NH4 + tid;
        ((float4*)pmax)[o] = mx;
        ((float4*)psum)[o] = sm;
        if (tid == 0) pcnt[b * NCH + ss] = n;
    } else {
        // ---------------- gap score ----------------
        const int bg = blk - NB * NCH;
        const int b = bg >> 4;
        const int g = bg & 15;

        if (tid == 0) s_misc[1] = gids[b * NG + g];
        __syncthreads();
        const int gi = s_misc[1];

        if (tid < 64) {  // wave 0 computes the 31 validity bits
            bool v = false;
            if (tid < WLEN) {
                const int idx = gi - WRAD + tid;
                v = (idx >= 0) && (idx < NS) && (tt[b * NS + idx] == 0) &&
                    (wm[b * NS + idx] != 0);
            }
            unsigned long long m = __ballot(v);
            if (tid == 0) s_wmask[0] = m;
        }
        __syncthreads();
        const unsigned long long vm = s_wmask[0];
        const float count = (float)__popcll(vm);

        const float4* rowbase = (const float4*)(seq + (size_t)b * NS * NH);
        const float4 gv = rowbase[(size_t)gi * NH4 + tid];

        float4 mx = ninf4;
        float4 sm = zero4;
#pragma unroll 4
        for (int j = 0; j < WLEN; ++j) {
            int idx = gi - WRAD + j;
            idx = idx < 0 ? 0 : (idx > NS - 1 ? NS - 1 : idx);
            const float4 v = rowbase[(size_t)idx * NH4 + tid];  // unconditional
            const bool val = (vm >> j) & 1ull;
            // branch-free select (v_cndmask), loads stay pipelined
            mx.x = val ? fmaxf(mx.x, v.x) : mx.x;
            mx.y = val ? fmaxf(mx.y, v.y) : mx.y;
            mx.z = val ? fmaxf(mx.z, v.z) : mx.z;
            mx.w = val ? fmaxf(mx.w, v.w) : mx.w;
            sm.x += val ? v.x : 0.f;
            sm.y += val ? v.y : 0.f;
            sm.z += val ? v.z : 0.f;
            sm.w += val ? v.w : 0.f;
        }
        const float4 wmax = f4max(mx, zero4);
        // plain division: count==0 -> 0/0 = NaN, matching the reference.
        const float4 wavg = make_float4(sm.x / count, sm.y / count,
                                        sm.z / count, sm.w / count);

        const float4* w0 = (const float4*)gapW;
        const float4* w1 = (const float4*)(gapW + NH);
        const float4* w2 = (const float4*)(gapW + 2 * NH);
        float part = f4dot(gv, w0[tid]) + f4dot(wmax, w1[tid]) + f4dot(wavg, w2[tid]);
        float total = block_reduce_192(part, sbuf);
        if (tid == 0) out[b * OUTW + 1 + g] = total + gapb[0];
    }
}

// ---------------------------------------------------------------------------
// cls kernel: one block per b, combines NCH partials + counts, fused dot.
// ---------------------------------------------------------------------------
__global__ __launch_bounds__(192) void cls_kernel(
    const float* __restrict__ pooled, const float* __restrict__ pmax,
    const float* __restrict__ psum, const int* __restrict__ pcnt,
    const float* __restrict__ clsW, const float* __restrict__ clsb,
    float* __restrict__ out) {
    const int b = blockIdx.x;
    const int tid = threadIdx.x;
    __shared__ float sbuf[256];

    float c = (tid < NCH) ? (float)pcnt[b * NCH + tid] : 0.f;
    const float count = block_reduce_192(c, sbuf);

    const float4* pm4 = (const float4*)pmax;
    const float4* ps4 = (const float4*)psum;
    float4 mx = make_float4(-INFINITY, -INFINITY, -INFINITY, -INFINITY);
    float4 sm = make_float4(0.f, 0.f, 0.f, 0.f);
#pragma unroll 8
    for (int ch = 0; ch < NCH; ++ch) {
        const size_t o = ((size_t)(b * NCH + ch)) * NH4 + tid;
        mx = f4max(mx, pm4[o]);
        sm = f4add(sm, ps4[o]);
    }
    const float4 zero4 = make_float4(0.f, 0.f, 0.f, 0.f);
    const float4 tmax = f4max(mx, zero4);
    const float4 tavg = make_float4(sm.x / count, sm.y / count,
                                    sm.z / count, sm.w / count);

    const float4* p4 = (const float4*)(pooled + (size_t)b * NH);
    const float4* w0 = (const float4*)clsW;
    const float4* w1 = (const float4*)(clsW + NH);
    const float4* w2 = (const float4*)(clsW + 2 * NH);
    float part = f4dot(p4[tid], w0[tid]) + f4dot(tmax, w1[tid]) + f4dot(tavg, w2[tid]);
    float total = block_reduce_192(part, sbuf);
    if (tid == 0) out[b * OUTW + 0] = total + clsb[0];
}

extern "C" void kernel_launch(void* const* d_in, const int* in_sizes, int n_in,
                              void* d_out, int out_size, void* d_ws, size_t ws_size,
                              hipStream_t stream) {
    const float* seq    = (const float*)d_in[0];  // [B,S,H] fp32
    const float* pooled = (const float*)d_in[1];  // [B,H]
    const int*   tt     = (const int*)d_in[2];    // [B,S]
    const int*   wm     = (const int*)d_in[3];    // [B,S]
    const int*   gids   = (const int*)d_in[4];    // [B,G]
    const float* gapW   = (const float*)d_in[5];  // [3H]
    const float* gapb   = (const float*)d_in[6];  // scalar
    const float* clsW   = (const float*)d_in[7];  // [3H]
    const float* clsb   = (const float*)d_in[8];  // scalar
    float* out = (float*)d_out;

    // ws layout: pmax | psum | pcnt  (all written by fused_kernel before read)
    float* pmax = (float*)d_ws;
    float* psum = pmax + (size_t)NB * NCH * NH;
    int*   pcnt = (int*)(psum + (size_t)NB * NCH * NH);

    fused_kernel<<<NB * NCH + NB * NG, 192, 0, stream>>>(
        seq, tt, wm, gids, gapW, gapb, pmax, psum, pcnt, out);
    cls_kernel<<<NB, 192, 0, stream>>>(pooled, pmax, psum, pcnt, clsW, clsb, out);
}